// Round 1
// baseline (1380.475 us; speedup 1.0000x reference)
//
#include <hip/hip_runtime.h>
#include <cstdint>

// Shapes (hard-coded for this problem): B=4, Cx=512, Cy=256, M=64, H=W=64, N=4096
constexpr int N_ = 4096;
constexpr int B_ = 4;
constexpr int SPLIT = 8;
constexpr int KEYS = N_ / SPLIT;  // 512 keys per split block

// ---------------- conv1x1: C[b][o0+i][n] = sum_c W[o0+i][c] * A[b][c][n] -----------
// W loads are wave-uniform -> scalar pipe; A loads coalesced; 16 outputs/thread.
__global__ __launch_bounds__(256) void conv_k(const float* __restrict__ W,
                                              const float* __restrict__ A,
                                              float* __restrict__ C, int K, int Ot) {
  const int n = blockIdx.x * 256 + threadIdx.x;
  const int b = blockIdx.y;
  const int o0 = blockIdx.z * 16;
  const float* Ap = A + (size_t)b * K * N_ + n;
  const float* Wp = W + (size_t)o0 * K;
  float acc[16];
#pragma unroll
  for (int i = 0; i < 16; ++i) acc[i] = 0.f;
#pragma unroll 4
  for (int c0 = 0; c0 < K; c0 += 8) {
    float a[8];
#pragma unroll
    for (int cc = 0; cc < 8; ++cc) a[cc] = Ap[(size_t)(c0 + cc) * N_];
#pragma unroll
    for (int i = 0; i < 16; ++i) {
#pragma unroll
      for (int cc = 0; cc < 8; ++cc) acc[i] += a[cc] * Wp[(size_t)i * K + c0 + cc];
    }
  }
  float* Cp = C + ((size_t)b * Ot + o0) * N_ + n;
#pragma unroll
  for (int i = 0; i < 16; ++i) Cp[(size_t)i * N_] = acc[i];
}

// ---------------- BN stats: per-channel mean/var over (B,N), biased ---------------
__global__ __launch_bounds__(1024) void bn_stats_k(const float* __restrict__ Z,
                                                   const float* __restrict__ g,
                                                   const float* __restrict__ bt,
                                                   float* __restrict__ scale,
                                                   float* __restrict__ shift, int C) {
  const int c = blockIdx.x;
  const int tid = threadIdx.x;
  float s = 0.f, ss = 0.f;
  for (int i = tid; i < B_ * N_; i += 1024) {
    int b = i >> 12;              // N = 4096 = 2^12
    int n = i & (N_ - 1);
    float v = Z[((size_t)b * C + c) * N_ + n];
    s += v;
    ss += v * v;
  }
  __shared__ float red0[1024];
  __shared__ float red1[1024];
  red0[tid] = s; red1[tid] = ss;
  __syncthreads();
  for (int st = 512; st > 0; st >>= 1) {
    if (tid < st) { red0[tid] += red0[tid + st]; red1[tid] += red1[tid + st]; }
    __syncthreads();
  }
  if (tid == 0) {
    const float cnt = (float)(B_ * N_);
    float mean = red0[0] / cnt;
    float var = red1[0] / cnt - mean * mean;
    float rstd = rsqrtf(var + 1e-5f);
    float sc = g[c] * rstd;
    scale[c] = sc;
    shift[c] = bt[c] - mean * sc;
  }
}

// ---------------- BN apply for [B,64,N] tensors (1,048,576 elements) --------------
__global__ __launch_bounds__(256) void bn_apply_k(const float* __restrict__ Zin,
                                                  float* __restrict__ Zout,
                                                  const float* __restrict__ scale,
                                                  const float* __restrict__ shift) {
  int idx = blockIdx.x * 256 + threadIdx.x;
  int c = (idx >> 12) & 63;
  Zout[idx] = Zin[idx] * scale[c] + shift[c];
}

// ---------------- flash attention, split-K over blocks ----------------------------
// One query per thread; K/V rows via wave-uniform (scalar) loads; Q column in LDS;
// acc[64] in VGPRs (PV fully unrolled -> static register indexing).
__global__ __launch_bounds__(64) void attn_k(const float* __restrict__ fx,
                                             const float* __restrict__ fy,
                                             const float* __restrict__ fs,
                                             float* __restrict__ pm,
                                             float* __restrict__ pl,
                                             float* __restrict__ pacc) {
  const int lane = threadIdx.x;
  const int b = blockIdx.y;
  const int sp = blockIdx.z;
  const int q = blockIdx.x * 64 + lane;
  const float* FX = fx + (size_t)b * 64 * N_;
  const float* FY = fy + (size_t)b * 64 * N_;
  const float* FS = fs + (size_t)b * 64 * N_;

  __shared__ float sQ[64 * 64];  // [m][lane]
  for (int m = 0; m < 64; ++m) sQ[m * 64 + lane] = FX[(size_t)m * N_ + q];
  __syncthreads();

  float acc[64];
#pragma unroll
  for (int m = 0; m < 64; ++m) acc[m] = 0.f;
  float mrun = -3.0e38f, lrun = 0.f;

  const int jbeg = sp * KEYS;
#pragma unroll 1
  for (int j0 = jbeg; j0 < jbeg + KEYS; j0 += 32) {
    float sc[32];
#pragma unroll
    for (int j = 0; j < 32; ++j) sc[j] = 0.f;
    // QK^T: sc[j] += q[m] * K[m][j0+j]   (K uniform -> s_load)
#pragma unroll 2
    for (int m = 0; m < 64; ++m) {
      float qm = sQ[m * 64 + lane];
      const float* kr = FY + (size_t)m * N_ + j0;
#pragma unroll
      for (int j = 0; j < 32; ++j) sc[j] += qm * kr[j];
    }
    // online softmax
    float tmax = sc[0];
#pragma unroll
    for (int j = 1; j < 32; ++j) tmax = fmaxf(tmax, sc[j]);
    float mnew = fmaxf(mrun, tmax);
    float alpha = __expf(mrun - mnew);  // first tile: exp(very negative) = 0
    float psum = 0.f;
#pragma unroll
    for (int j = 0; j < 32; ++j) { sc[j] = __expf(sc[j] - mnew); psum += sc[j]; }
    lrun = lrun * alpha + psum;
    mrun = mnew;
    // PV: acc[m] = acc[m]*alpha + sum_j p[j] * V[m][j0+j]  (fully unrolled)
#pragma unroll
    for (int m = 0; m < 64; ++m) {
      const float* vr = FS + (size_t)m * N_ + j0;
      float am = acc[m] * alpha;
#pragma unroll
      for (int j = 0; j < 32; ++j) am += sc[j] * vr[j];
      acc[m] = am;
    }
  }
  size_t pbase = ((size_t)sp * B_ + b) * N_ + q;
  pm[pbase] = mrun;
  pl[pbase] = lrun;
  size_t abase = (((size_t)sp * B_ + b) * 64) * (size_t)N_ + q;
#pragma unroll
  for (int m = 0; m < 64; ++m) pacc[abase + (size_t)m * N_] = acc[m];
}

// ---------------- combine split-K partials ---------------------------------------
__global__ __launch_bounds__(256) void attn_combine_k(const float* __restrict__ pm,
                                                      const float* __restrict__ pl,
                                                      const float* __restrict__ pacc,
                                                      float* __restrict__ fout) {
  const int q = blockIdx.x * 256 + threadIdx.x;
  const int b = blockIdx.y;
  float ms[SPLIT], ws[SPLIT];
  float mt = -3.0e38f;
#pragma unroll
  for (int s = 0; s < SPLIT; ++s) {
    ms[s] = pm[((size_t)s * B_ + b) * N_ + q];
    mt = fmaxf(mt, ms[s]);
  }
  float lt = 0.f;
#pragma unroll
  for (int s = 0; s < SPLIT; ++s) {
    ws[s] = __expf(ms[s] - mt);
    lt += ws[s] * pl[((size_t)s * B_ + b) * N_ + q];
  }
  float inv = 1.f / lt;
  for (int m = 0; m < 64; ++m) {
    float o = 0.f;
#pragma unroll
    for (int s = 0; s < SPLIT; ++s)
      o += ws[s] * pacc[(((size_t)s * B_ + b) * 64 + m) * (size_t)N_ + q];
    fout[((size_t)b * 64 + m) * N_ + q] = o * inv;
  }
}

// ---------------- residual + final BN --------------------------------------------
__global__ __launch_bounds__(256) void final_k(const float* __restrict__ x,
                                               const float* __restrict__ u,
                                               const float* __restrict__ scale,
                                               const float* __restrict__ shift,
                                               float* __restrict__ out) {
  size_t idx = (size_t)blockIdx.x * 256 + threadIdx.x;
  int c = (int)((idx >> 12) & 511);
  out[idx] = x[idx] + u[idx] * scale[c] + shift[c];
}

extern "C" void kernel_launch(void* const* d_in, const int* in_sizes, int n_in,
                              void* d_out, int out_size, void* d_ws, size_t ws_size,
                              hipStream_t stream) {
  const float* x = (const float*)d_in[0];
  const float* y = (const float*)d_in[1];
  const float* ws1 = (const float*)d_in[2];
  const float* gs1 = (const float*)d_in[3];
  const float* bs1 = (const float*)d_in[4];
  const float* ws2 = (const float*)d_in[5];
  const float* gs2 = (const float*)d_in[6];
  const float* bs2 = (const float*)d_in[7];
  const float* wx1 = (const float*)d_in[8];
  const float* gx1 = (const float*)d_in[9];
  const float* bx1 = (const float*)d_in[10];
  const float* wx2 = (const float*)d_in[11];
  const float* gx2 = (const float*)d_in[12];
  const float* bx2 = (const float*)d_in[13];
  const float* wy1 = (const float*)d_in[14];
  const float* gy1 = (const float*)d_in[15];
  const float* by1 = (const float*)d_in[16];
  const float* wy2 = (const float*)d_in[17];
  const float* gy2 = (const float*)d_in[18];
  const float* by2 = (const float*)d_in[19];
  const float* wu = (const float*)d_in[20];
  const float* gu = (const float*)d_in[21];
  const float* bu = (const float*)d_in[22];
  float* out = (float*)d_out;

  float* w = (float*)d_ws;
  const size_t MB1 = 1048576;  // elements of one [B,64,N] f32 tensor
  float* zbuf = w;
  float* zbuf2 = w + 1 * MB1;
  float* fself = w + 2 * MB1;
  float* fx = w + 3 * MB1;
  float* fy = w + 4 * MB1;
  float* fout = w + 5 * MB1;
  float* u = w + 6 * MB1;          // 8M floats [B,512,N]
  float* pm = w + 14 * MB1;        // SPLIT*B*N = 131072
  float* pl = pm + (size_t)SPLIT * B_ * N_;
  float* pacc = pl + (size_t)SPLIT * B_ * N_;  // SPLIT*B*64*N = 8,388,608
  float* scale = pacc + (size_t)SPLIT * B_ * 64 * N_;
  float* shift = scale + 512;

  dim3 blk(256);
  auto conv = [&](const float* W, const float* A, float* C, int K, int Ot) {
    conv_k<<<dim3(N_ / 256, B_, Ot / 16), blk, 0, stream>>>(W, A, C, K, Ot);
  };
  auto stats = [&](const float* Z, const float* g, const float* bt, int C) {
    bn_stats_k<<<dim3(C), dim3(1024), 0, stream>>>(Z, g, bt, scale, shift, C);
  };
  auto apply = [&](const float* Zin, float* Zout) {
    bn_apply_k<<<dim3((B_ * 64 * N_) / 256), blk, 0, stream>>>(Zin, Zout, scale, shift);
  };

  // f_self = bn(ws2 @ bn(ws1 @ x))
  conv(ws1, x, zbuf, 512, 64);
  stats(zbuf, gs1, bs1, 64);
  apply(zbuf, zbuf);
  conv(ws2, zbuf, zbuf2, 64, 64);
  stats(zbuf2, gs2, bs2, 64);
  apply(zbuf2, fself);
  // f_x
  conv(wx1, x, zbuf, 512, 64);
  stats(zbuf, gx1, bx1, 64);
  apply(zbuf, zbuf);
  conv(wx2, zbuf, zbuf2, 64, 64);
  stats(zbuf2, gx2, bx2, 64);
  apply(zbuf2, fx);
  // f_y
  conv(wy1, y, zbuf, 256, 64);
  stats(zbuf, gy1, by1, 64);
  apply(zbuf, zbuf);
  conv(wy2, zbuf, zbuf2, 64, 64);
  stats(zbuf2, gy2, by2, 64);
  apply(zbuf2, fy);

  // attention: softmax(fx^T fy) @ fself^T, split-K flash
  attn_k<<<dim3(N_ / 64, B_, SPLIT), dim3(64), 0, stream>>>(fx, fy, fself, pm, pl, pacc);
  attn_combine_k<<<dim3(N_ / 256, B_), blk, 0, stream>>>(pm, pl, pacc, fout);

  // f_up + residual
  conv(wu, fout, u, 64, 512);
  stats(u, gu, bu, 512);
  final_k<<<dim3((B_ * 512 * N_) / 256), blk, 0, stream>>>(x, u, scale, shift, out);
}

// Round 3
// 996.307 us; speedup vs baseline: 1.3856x; 1.3856x over previous
//
#include <hip/hip_runtime.h>
#include <hip/hip_bf16.h>
#include <cstdint>

// Shapes (hard-coded): B=4, Cx=512, Cy=256, M=64, H=W=64, N=4096
constexpr int N_ = 4096;
constexpr int B_ = 4;

typedef __attribute__((ext_vector_type(8))) short short8;
typedef __attribute__((ext_vector_type(4))) float f32x4;

union frag { short8 s8; int i4[4]; };

__device__ inline int pkbf(float a, float b) {
  union { __hip_bfloat162 h; int i; } u;
  u.h = __float22bfloat162_rn(float2{a, b});
  return u.i;
}
// split a,b into hi/lo bf16 pairs: v = hi + lo with ~16-bit effective mantissa
__device__ inline void split2(float a, float b, int& hi, int& lo) {
  union { __hip_bfloat162 h; int i; } uh, ul;
  uh.h = __float22bfloat162_rn(float2{a, b});
  float2 hf = __bfloat1622float2(uh.h);
  ul.h = __float22bfloat162_rn(float2{a - hf.x, b - hf.y});
  hi = uh.i;
  lo = ul.i;
}

// ---------------- conv1x1: C[b][o0+i][n] = sum_c W[o0+i][c] * A[b][c][n] -----------
__global__ __launch_bounds__(256) void conv_k(const float* __restrict__ W,
                                              const float* __restrict__ A,
                                              float* __restrict__ C, int K, int Ot) {
  const int n = blockIdx.x * 256 + threadIdx.x;
  const int b = blockIdx.y;
  const int o0 = blockIdx.z * 16;
  const float* Ap = A + (size_t)b * K * N_ + n;
  const float* Wp = W + (size_t)o0 * K;
  float acc[16];
#pragma unroll
  for (int i = 0; i < 16; ++i) acc[i] = 0.f;
#pragma unroll 4
  for (int c0 = 0; c0 < K; c0 += 8) {
    float a[8];
#pragma unroll
    for (int cc = 0; cc < 8; ++cc) a[cc] = Ap[(size_t)(c0 + cc) * N_];
#pragma unroll
    for (int i = 0; i < 16; ++i) {
#pragma unroll
      for (int cc = 0; cc < 8; ++cc) acc[i] += a[cc] * Wp[(size_t)i * K + c0 + cc];
    }
  }
  float* Cp = C + ((size_t)b * Ot + o0) * N_ + n;
#pragma unroll
  for (int i = 0; i < 16; ++i) Cp[(size_t)i * N_] = acc[i];
}

// ---------------- BN stats ---------------
__global__ __launch_bounds__(1024) void bn_stats_k(const float* __restrict__ Z,
                                                   const float* __restrict__ g,
                                                   const float* __restrict__ bt,
                                                   float* __restrict__ scale,
                                                   float* __restrict__ shift, int C) {
  const int c = blockIdx.x;
  const int tid = threadIdx.x;
  float s = 0.f, ss = 0.f;
  for (int i = tid; i < B_ * N_; i += 1024) {
    int b = i >> 12;
    int n = i & (N_ - 1);
    float v = Z[((size_t)b * C + c) * N_ + n];
    s += v;
    ss += v * v;
  }
  __shared__ float red0[1024];
  __shared__ float red1[1024];
  red0[tid] = s; red1[tid] = ss;
  __syncthreads();
  for (int st = 512; st > 0; st >>= 1) {
    if (tid < st) { red0[tid] += red0[tid + st]; red1[tid] += red1[tid + st]; }
    __syncthreads();
  }
  if (tid == 0) {
    const float cnt = (float)(B_ * N_);
    float mean = red0[0] / cnt;
    float var = red1[0] / cnt - mean * mean;
    float rstd = rsqrtf(var + 1e-5f);
    float sc = g[c] * rstd;
    scale[c] = sc;
    shift[c] = bt[c] - mean * sc;
  }
}

// ---------------- BN apply for [B,64,N] --------------
__global__ __launch_bounds__(256) void bn_apply_k(const float* __restrict__ Zin,
                                                  float* __restrict__ Zout,
                                                  const float* __restrict__ scale,
                                                  const float* __restrict__ shift) {
  int idx = blockIdx.x * 256 + threadIdx.x;
  int c = (idx >> 12) & 63;
  Zout[idx] = Zin[idx] * scale[c] + shift[c];
}

// ---------------- MFMA bf16x2 flash attention --------------------------------------
// Block = 4 waves x 16 queries (shared); each wave sweeps N/4 keys; block-level
// split-K combine in LDS. QK^T in split bf16 (qh*kh + ql*kh + qh*kl) for ~f32
// logit accuracy; P and V single bf16 (error ~1e-2, fine for 0.1725 threshold).
__global__ __launch_bounds__(256) void attn_mfma_k(const float* __restrict__ fx,
                                                   const float* __restrict__ fy,
                                                   const float* __restrict__ fs,
                                                   float* __restrict__ fout) {
  const int tid = threadIdx.x;
  const int lane = tid & 63;
  const int wid = tid >> 6;
  const int la = lane & 15;
  const int quad = lane >> 4;
  const int b = blockIdx.y;
  const int qbase = blockIdx.x * 16;
  const float* FX = fx + (size_t)b * 64 * N_;
  const float* FY = fy + (size_t)b * 64 * N_;
  const float* FS = fs + (size_t)b * 64 * N_;

  __shared__ float sP[4][16 * 36];
  __shared__ float sM[4][16], sL[4][16];
  __shared__ float sO[4][16][64];
  float* myP = sP[wid];

  // Q A-frags (hi/lo): A[m=la][k=quad*8+j], k-halves c=0: ch 0-31, c=1: ch 32-63
  frag aqh[2], aql[2];
#pragma unroll
  for (int c = 0; c < 2; ++c) {
#pragma unroll
    for (int j = 0; j < 4; ++j) {
      float a = FX[(size_t)(c * 32 + quad * 8 + 2 * j) * N_ + qbase + la];
      float bb = FX[(size_t)(c * 32 + quad * 8 + 2 * j + 1) * N_ + qbase + la];
      split2(a, bb, aqh[c].i4[j], aql[c].i4[j]);
    }
  }

  f32x4 o[4];
  float mrun[4], lrun[4];
#pragma unroll
  for (int mt = 0; mt < 4; ++mt) o[mt] = f32x4{0.f, 0.f, 0.f, 0.f};
#pragma unroll
  for (int r = 0; r < 4; ++r) { mrun[r] = -3.0e38f; lrun[r] = 0.f; }

  const int jbeg = wid * (N_ / 4);
#pragma unroll 1
  for (int j0 = jbeg; j0 < jbeg + N_ / 4; j0 += 32) {
    // ---- QK^T on 32 keys (2 groups of 16) ----
    f32x4 s[2];
#pragma unroll
    for (int nt = 0; nt < 2; ++nt) {
      frag kh0, kh1, kl0, kl1;
      const int key = j0 + nt * 16 + la;
#pragma unroll
      for (int jj = 0; jj < 4; ++jj) {
        const float* k0 = &FY[(size_t)(quad * 8 + 2 * jj) * N_ + key];
        split2(k0[0], k0[N_], kh0.i4[jj], kl0.i4[jj]);
        const float* k1 = &FY[(size_t)(32 + quad * 8 + 2 * jj) * N_ + key];
        split2(k1[0], k1[N_], kh1.i4[jj], kl1.i4[jj]);
      }
      f32x4 z = f32x4{0.f, 0.f, 0.f, 0.f};
      z = __builtin_amdgcn_mfma_f32_16x16x32_bf16(aqh[0].s8, kh0.s8, z, 0, 0, 0);
      z = __builtin_amdgcn_mfma_f32_16x16x32_bf16(aqh[1].s8, kh1.s8, z, 0, 0, 0);
      z = __builtin_amdgcn_mfma_f32_16x16x32_bf16(aql[0].s8, kh0.s8, z, 0, 0, 0);
      z = __builtin_amdgcn_mfma_f32_16x16x32_bf16(aql[1].s8, kh1.s8, z, 0, 0, 0);
      z = __builtin_amdgcn_mfma_f32_16x16x32_bf16(aqh[0].s8, kl0.s8, z, 0, 0, 0);
      z = __builtin_amdgcn_mfma_f32_16x16x32_bf16(aqh[1].s8, kl1.s8, z, 0, 0, 0);
      s[nt] = z;
    }
    // ---- online softmax over 32 keys (C-layout: col=la=key, row=quad*4+r) ----
    float alpha[4];
#pragma unroll
    for (int r = 0; r < 4; ++r) {
      float t = fmaxf(s[0][r], s[1][r]);
      t = fmaxf(t, __shfl_xor(t, 1));
      t = fmaxf(t, __shfl_xor(t, 2));
      t = fmaxf(t, __shfl_xor(t, 4));
      t = fmaxf(t, __shfl_xor(t, 8));
      float mnew = fmaxf(mrun[r], t);
      alpha[r] = __expf(mrun[r] - mnew);
      float p0 = __expf(s[0][r] - mnew);
      float p1 = __expf(s[1][r] - mnew);
      s[0][r] = p0; s[1][r] = p1;
      float ps = p0 + p1;
      ps += __shfl_xor(ps, 1);
      ps += __shfl_xor(ps, 2);
      ps += __shfl_xor(ps, 4);
      ps += __shfl_xor(ps, 8);
      lrun[r] = lrun[r] * alpha[r] + ps;
      mrun[r] = mnew;
    }
    // ---- P -> LDS (row=query, col=key, stride 36) ----
#pragma unroll
    for (int nt = 0; nt < 2; ++nt)
#pragma unroll
      for (int r = 0; r < 4; ++r)
        myP[(quad * 4 + r) * 36 + nt * 16 + la] = s[nt][r];
    __asm__ __volatile__("s_waitcnt lgkmcnt(0)" ::: "memory");
    // ---- read P as A-frag: A[m=la][k=quad*8+jj] ----
    frag pa;
    {
      const f32x4* pr = (const f32x4*)&myP[la * 36 + quad * 8];
      f32x4 p0 = pr[0], p1 = pr[1];
      pa.i4[0] = pkbf(p0[0], p0[1]);
      pa.i4[1] = pkbf(p0[2], p0[3]);
      pa.i4[2] = pkbf(p1[0], p1[1]);
      pa.i4[3] = pkbf(p1[2], p1[3]);
    }
    // ---- rescale O, then PV ----
#pragma unroll
    for (int mt = 0; mt < 4; ++mt)
#pragma unroll
      for (int r = 0; r < 4; ++r) o[mt][r] *= alpha[r];
#pragma unroll
    for (int mt = 0; mt < 4; ++mt) {
      const f32x4* vp = (const f32x4*)&FS[(size_t)(mt * 16 + la) * N_ + j0 + quad * 8];
      f32x4 v0 = vp[0], v1 = vp[1];
      frag vb;
      vb.i4[0] = pkbf(v0[0], v0[1]);
      vb.i4[1] = pkbf(v0[2], v0[3]);
      vb.i4[2] = pkbf(v1[0], v1[1]);
      vb.i4[3] = pkbf(v1[2], v1[3]);
      o[mt] = __builtin_amdgcn_mfma_f32_16x16x32_bf16(pa.s8, vb.s8, o[mt], 0, 0, 0);
    }
  }

  // ---- block-level split-K combine in LDS ----
  if (la == 0) {
#pragma unroll
    for (int r = 0; r < 4; ++r) {
      sM[wid][quad * 4 + r] = mrun[r];
      sL[wid][quad * 4 + r] = lrun[r];
    }
  }
#pragma unroll
  for (int mt = 0; mt < 4; ++mt)
#pragma unroll
    for (int r = 0; r < 4; ++r) sO[wid][quad * 4 + r][mt * 16 + la] = o[mt][r];
  __syncthreads();

#pragma unroll
  for (int t = 0; t < 4; ++t) {
    int oidx = t * 256 + tid;       // 1024 outputs: 16 q x 64 m
    int m = oidx >> 4;
    int q = oidx & 15;
    float m0 = fmaxf(fmaxf(sM[0][q], sM[1][q]), fmaxf(sM[2][q], sM[3][q]));
    float num = 0.f, den = 0.f;
#pragma unroll
    for (int w = 0; w < 4; ++w) {
      float wgt = __expf(sM[w][q] - m0);
      num += wgt * sO[w][q][m];
      den += wgt * sL[w][q];
    }
    fout[((size_t)b * 64 + m) * N_ + qbase + q] = num / den;
  }
}

// ---------------- residual + final BN --------------------------------------------
__global__ __launch_bounds__(256) void final_k(const float* __restrict__ x,
                                               const float* __restrict__ u,
                                               const float* __restrict__ scale,
                                               const float* __restrict__ shift,
                                               float* __restrict__ out) {
  size_t idx = (size_t)blockIdx.x * 256 + threadIdx.x;
  int c = (int)((idx >> 12) & 511);
  out[idx] = x[idx] + u[idx] * scale[c] + shift[c];
}

extern "C" void kernel_launch(void* const* d_in, const int* in_sizes, int n_in,
                              void* d_out, int out_size, void* d_ws, size_t ws_size,
                              hipStream_t stream) {
  const float* x = (const float*)d_in[0];
  const float* y = (const float*)d_in[1];
  const float* ws1 = (const float*)d_in[2];
  const float* gs1 = (const float*)d_in[3];
  const float* bs1 = (const float*)d_in[4];
  const float* ws2 = (const float*)d_in[5];
  const float* gs2 = (const float*)d_in[6];
  const float* bs2 = (const float*)d_in[7];
  const float* wx1 = (const float*)d_in[8];
  const float* gx1 = (const float*)d_in[9];
  const float* bx1 = (const float*)d_in[10];
  const float* wx2 = (const float*)d_in[11];
  const float* gx2 = (const float*)d_in[12];
  const float* bx2 = (const float*)d_in[13];
  const float* wy1 = (const float*)d_in[14];
  const float* gy1 = (const float*)d_in[15];
  const float* by1 = (const float*)d_in[16];
  const float* wy2 = (const float*)d_in[17];
  const float* gy2 = (const float*)d_in[18];
  const float* by2 = (const float*)d_in[19];
  const float* wu = (const float*)d_in[20];
  const float* gu = (const float*)d_in[21];
  const float* bu = (const float*)d_in[22];
  float* out = (float*)d_out;

  float* w = (float*)d_ws;
  const size_t MB1 = 1048576;  // elements of one [B,64,N] f32 tensor
  float* zbuf = w;
  float* zbuf2 = w + 1 * MB1;
  float* fself = w + 2 * MB1;
  float* fx = w + 3 * MB1;
  float* fy = w + 4 * MB1;
  float* fout = w + 5 * MB1;
  float* u = w + 6 * MB1;          // 8M floats [B,512,N]
  float* scale = w + 14 * MB1;
  float* shift = scale + 512;

  dim3 blk(256);
  auto conv = [&](const float* W, const float* A, float* C, int K, int Ot) {
    conv_k<<<dim3(N_ / 256, B_, Ot / 16), blk, 0, stream>>>(W, A, C, K, Ot);
  };
  auto stats = [&](const float* Z, const float* g, const float* bt, int C) {
    bn_stats_k<<<dim3(C), dim3(1024), 0, stream>>>(Z, g, bt, scale, shift, C);
  };
  auto apply = [&](const float* Zin, float* Zout) {
    bn_apply_k<<<dim3((B_ * 64 * N_) / 256), blk, 0, stream>>>(Zin, Zout, scale, shift);
  };

  // f_self
  conv(ws1, x, zbuf, 512, 64);
  stats(zbuf, gs1, bs1, 64);
  apply(zbuf, zbuf);
  conv(ws2, zbuf, zbuf2, 64, 64);
  stats(zbuf2, gs2, bs2, 64);
  apply(zbuf2, fself);
  // f_x
  conv(wx1, x, zbuf, 512, 64);
  stats(zbuf, gx1, bx1, 64);
  apply(zbuf, zbuf);
  conv(wx2, zbuf, zbuf2, 64, 64);
  stats(zbuf2, gx2, bx2, 64);
  apply(zbuf2, fx);
  // f_y
  conv(wy1, y, zbuf, 256, 64);
  stats(zbuf, gy1, by1, 64);
  apply(zbuf, zbuf);
  conv(wy2, zbuf, zbuf2, 64, 64);
  stats(zbuf2, gy2, by2, 64);
  apply(zbuf2, fy);

  // attention: softmax(fx^T fy) @ fself^T  (MFMA split-bf16 flash, block split-K)
  attn_mfma_k<<<dim3(N_ / 16, B_), dim3(256), 0, stream>>>(fx, fy, fself, fout);

  // f_up + residual
  conv(wu, fout, u, 64, 512);
  stats(u, gu, bu, 512);
  final_k<<<dim3((B_ * 512 * N_) / 256), blk, 0, stream>>>(x, u, scale, shift, out);
}

// Round 4
// 816.317 us; speedup vs baseline: 1.6911x; 1.2205x over previous
//
#include <hip/hip_runtime.h>
#include <hip/hip_bf16.h>
#include <hip/hip_fp16.h>
#include <cstdint>

// Shapes (hard-coded): B=4, Cx=512, Cy=256, M=64, H=W=64, N=4096
constexpr int N_ = 4096;
constexpr int B_ = 4;
constexpr float CNT = 16384.f;  // B_*N_ reduction count for BN stats

typedef __attribute__((ext_vector_type(8))) _Float16 half8;
typedef __attribute__((ext_vector_type(4))) float f32x4;
union fragh { half8 h8; int i4[4]; };

__device__ inline int pkh(float a, float b) {
  union { __half2 h; int i; } u;
  u.h = __float22half2_rn(float2{a, b});
  return u.i;
}

// Stats buffer layout (floats): group g in {0:s1,1:x1,2:y1,3:s2,4:x2,5:y2}:
//   sum at g*128+c, sumsq at g*128+64+c  (c<64)
// f_up (512 ch): sum at 768+c, sumsq at 1280+c.  Total 1792 floats.

// ---------------- stage-1 convs (ws1, wx1, wy1) in one dispatch --------------------
__global__ __launch_bounds__(256) void conv1_k(
    const float* __restrict__ x, const float* __restrict__ y,
    const float* __restrict__ ws1, const float* __restrict__ wx1,
    const float* __restrict__ wy1,
    float* __restrict__ z1s, float* __restrict__ z1x, float* __restrict__ z1y,
    float* __restrict__ stats) {
  const int n = blockIdx.x * 256 + threadIdx.x;
  const int b = blockIdx.y;
  const int z = blockIdx.z;
  const int branch = z >> 3;          // 0:s 1:x 2:y
  const int o0 = (z & 7) * 8;
  const float* in = branch < 2 ? x : y;
  const int K = branch < 2 ? 512 : 256;
  const float* W = branch == 0 ? ws1 : (branch == 1 ? wx1 : wy1);
  float* out = branch == 0 ? z1s : (branch == 1 ? z1x : z1y);
  float* st = stats + branch * 128;

  const float* Ap = in + (size_t)b * K * N_ + n;
  const float* Wp = W + (size_t)o0 * K;
  float acc[8];
#pragma unroll
  for (int i = 0; i < 8; ++i) acc[i] = 0.f;
#pragma unroll 2
  for (int c0 = 0; c0 < K; c0 += 8) {
    float a[8];
#pragma unroll
    for (int cc = 0; cc < 8; ++cc) a[cc] = Ap[(size_t)(c0 + cc) * N_];
#pragma unroll
    for (int i = 0; i < 8; ++i)
#pragma unroll
      for (int cc = 0; cc < 8; ++cc) acc[i] += a[cc] * Wp[(size_t)i * K + c0 + cc];
  }
  float* Cp = out + ((size_t)b * 64 + o0) * N_ + n;
#pragma unroll
  for (int i = 0; i < 8; ++i) Cp[(size_t)i * N_] = acc[i];
  // per-wave (sum, sumsq) reduce, one atomic per wave per channel
  const int lane = threadIdx.x & 63;
#pragma unroll
  for (int i = 0; i < 8; ++i) {
    float s = acc[i], q = acc[i] * acc[i];
#pragma unroll
    for (int d = 1; d < 64; d <<= 1) { s += __shfl_xor(s, d); q += __shfl_xor(q, d); }
    if (lane == 0) {
      atomicAdd(&st[o0 + i], s);
      atomicAdd(&st[64 + o0 + i], q);
    }
  }
}

// ---------------- stage-2 convs (K=64) with inline stage-1 BN ----------------------
__global__ __launch_bounds__(256) void conv2_k(
    const float* __restrict__ z1s, const float* __restrict__ z1x,
    const float* __restrict__ z1y,
    const float* __restrict__ ws2, const float* __restrict__ wx2,
    const float* __restrict__ wy2,
    const float* __restrict__ gs1, const float* __restrict__ bs1,
    const float* __restrict__ gx1, const float* __restrict__ bx1,
    const float* __restrict__ gy1, const float* __restrict__ by1,
    float* __restrict__ z2s, float* __restrict__ z2x, float* __restrict__ z2y,
    float* __restrict__ stats) {
  const int n = blockIdx.x * 256 + threadIdx.x;
  const int b = blockIdx.y;
  const int branch = blockIdx.z >> 3;
  const int o0 = (blockIdx.z & 7) * 8;
  const float* in = branch == 0 ? z1s : (branch == 1 ? z1x : z1y);
  const float* W = branch == 0 ? ws2 : (branch == 1 ? wx2 : wy2);
  const float* g1 = branch == 0 ? gs1 : (branch == 1 ? gx1 : gy1);
  const float* b1 = branch == 0 ? bs1 : (branch == 1 ? bx1 : by1);
  float* out = branch == 0 ? z2s : (branch == 1 ? z2x : z2y);
  const float* stin = stats + branch * 128;
  float* stout = stats + (3 + branch) * 128;

  __shared__ float sc[64], sh[64];
  if (threadIdx.x < 64) {
    int c = threadIdx.x;
    float mean = stin[c] * (1.f / CNT);
    float var = stin[64 + c] * (1.f / CNT) - mean * mean;
    float r = rsqrtf(var + 1e-5f);
    float s = g1[c] * r;
    sc[c] = s;
    sh[c] = b1[c] - mean * s;
  }
  __syncthreads();

  const float* Ap = in + (size_t)b * 64 * N_ + n;
  const float* Wp = W + (size_t)o0 * 64;
  float acc[8];
#pragma unroll
  for (int i = 0; i < 8; ++i) acc[i] = 0.f;
#pragma unroll
  for (int c0 = 0; c0 < 64; c0 += 8) {
    float a[8];
#pragma unroll
    for (int cc = 0; cc < 8; ++cc)
      a[cc] = Ap[(size_t)(c0 + cc) * N_] * sc[c0 + cc] + sh[c0 + cc];
#pragma unroll
    for (int i = 0; i < 8; ++i)
#pragma unroll
      for (int cc = 0; cc < 8; ++cc) acc[i] += a[cc] * Wp[(size_t)i * 64 + c0 + cc];
  }
  float* Cp = out + ((size_t)b * 64 + o0) * N_ + n;
#pragma unroll
  for (int i = 0; i < 8; ++i) Cp[(size_t)i * N_] = acc[i];
  const int lane = threadIdx.x & 63;
#pragma unroll
  for (int i = 0; i < 8; ++i) {
    float s = acc[i], q = acc[i] * acc[i];
#pragma unroll
    for (int d = 1; d < 64; d <<= 1) { s += __shfl_xor(s, d); q += __shfl_xor(q, d); }
    if (lane == 0) {
      atomicAdd(&stout[o0 + i], s);
      atomicAdd(&stout[64 + o0 + i], q);
    }
  }
}

// ---------------- pack Q/K/V to fp16 packed-pair planar with inline stage-2 BN -----
// Qh,Kh: [b][c=0..31][n] int = half2(ch 2c, 2c+1).  Vp: [b][ch][k=0..2047] int =
// half2(key 2k, 2k+1).
__global__ __launch_bounds__(256) void pack_k(
    const float* __restrict__ z2s, const float* __restrict__ z2x,
    const float* __restrict__ z2y,
    const float* __restrict__ gs2, const float* __restrict__ bs2,
    const float* __restrict__ gx2, const float* __restrict__ bx2,
    const float* __restrict__ gy2, const float* __restrict__ by2,
    int* __restrict__ Qh, int* __restrict__ Kh, int* __restrict__ Vp,
    const float* __restrict__ stats) {
  const int job = blockIdx.z;  // 0: Q<-x2, 1: K<-y2, 2: V<-s2
  const int idx = blockIdx.x * 256 + threadIdx.x;  // 0..524287
  const float* z2 = job == 0 ? z2x : (job == 1 ? z2y : z2s);
  const float* g2 = job == 0 ? gx2 : (job == 1 ? gy2 : gs2);
  const float* b2 = job == 0 ? bx2 : (job == 1 ? by2 : bs2);
  const float* st = stats + (job == 0 ? 4 : (job == 1 ? 5 : 3)) * 128;
  int* outp = job == 0 ? Qh : (job == 1 ? Kh : Vp);

  auto snorm = [&](int c, float& s, float& h) {
    float mean = st[c] * (1.f / CNT);
    float var = st[64 + c] * (1.f / CNT) - mean * mean;
    float r = rsqrtf(var + 1e-5f);
    s = g2[c] * r;
    h = b2[c] - mean * s;
  };
  if (job < 2) {
    int n = idx & 4095, c = (idx >> 12) & 31, b = idx >> 17;
    float s0, h0, s1, h1;
    snorm(2 * c, s0, h0);
    snorm(2 * c + 1, s1, h1);
    float v0 = z2[((size_t)b * 64 + 2 * c) * N_ + n] * s0 + h0;
    float v1 = z2[((size_t)b * 64 + 2 * c + 1) * N_ + n] * s1 + h1;
    outp[idx] = pkh(v0, v1);
  } else {
    int k = idx & 2047, ch = (idx >> 11) & 63, b = idx >> 17;
    float s0, h0;
    snorm(ch, s0, h0);
    float2 v = *(const float2*)&z2[((size_t)b * 64 + ch) * N_ + 2 * k];
    outp[idx] = pkh(v.x * s0 + h0, v.y * s0 + h0);
  }
}

// ---------------- MFMA fp16 flash attention ----------------------------------------
// Block = 4 waves sharing 16 queries; wave sweeps N/4 keys; LDS split-K combine.
// All operands pre-packed fp16 -> zero conversion VALU in the QK path.
// b = blockIdx.x & 3 pins one batch per XCD (K/V L2-resident).
__global__ __launch_bounds__(256) void attn_k(const int* __restrict__ Qh,
                                              const int* __restrict__ Kh,
                                              const int* __restrict__ Vp,
                                              float* __restrict__ fout) {
  const int tid = threadIdx.x;
  const int lane = tid & 63;
  const int wid = tid >> 6;
  const int la = lane & 15;
  const int quad = lane >> 4;
  const int b = blockIdx.x & 3;
  const int qbase = (blockIdx.x >> 2) * 16;
  const int* Qb = Qh + (size_t)b * 32 * N_;
  const int* Kb = Kh + (size_t)b * 32 * N_;
  const int* Vb = Vp + (size_t)b * 64 * 2048;

  __shared__ union USm {
    float P[4][16 * 36];                                      // loop phase
    struct { float O[4][16][68]; float M[4][16]; float L[4][16]; } e;  // epilogue
  } smu;
  float* myP = smu.P[wid];

  // Q A-frag: A[m=la][k=quad*8+2j+{0,1}] -> packed c-index c*16+quad*4+j
  fragh aq[2];
#pragma unroll
  for (int c = 0; c < 2; ++c)
#pragma unroll
    for (int j = 0; j < 4; ++j)
      aq[c].i4[j] = Qb[(size_t)(c * 16 + quad * 4 + j) * N_ + qbase + la];

  f32x4 o[4];
  float mrun[4], lrun[4];
#pragma unroll
  for (int mt = 0; mt < 4; ++mt) o[mt] = f32x4{0.f, 0.f, 0.f, 0.f};
#pragma unroll
  for (int r = 0; r < 4; ++r) { mrun[r] = -3.0e38f; lrun[r] = 0.f; }

  const int jbeg = wid * (N_ / 4);
#pragma unroll 1
  for (int j0 = jbeg; j0 < jbeg + N_ / 4; j0 += 32) {
    // ---- QK^T on 32 keys ----
    f32x4 s[2];
#pragma unroll
    for (int nt = 0; nt < 2; ++nt) {
      fragh k0, k1;
      const int key = j0 + nt * 16 + la;
#pragma unroll
      for (int jj = 0; jj < 4; ++jj) {
        k0.i4[jj] = Kb[(size_t)(quad * 4 + jj) * N_ + key];
        k1.i4[jj] = Kb[(size_t)(16 + quad * 4 + jj) * N_ + key];
      }
      f32x4 z = f32x4{0.f, 0.f, 0.f, 0.f};
      z = __builtin_amdgcn_mfma_f32_16x16x32_f16(aq[0].h8, k0.h8, z, 0, 0, 0);
      s[nt] = __builtin_amdgcn_mfma_f32_16x16x32_f16(aq[1].h8, k1.h8, z, 0, 0, 0);
    }
    // ---- online softmax (C-layout: col=la=key, row=quad*4+r=query) ----
    float alpha[4];
#pragma unroll
    for (int r = 0; r < 4; ++r) {
      float t = fmaxf(s[0][r], s[1][r]);
      t = fmaxf(t, __shfl_xor(t, 1));
      t = fmaxf(t, __shfl_xor(t, 2));
      t = fmaxf(t, __shfl_xor(t, 4));
      t = fmaxf(t, __shfl_xor(t, 8));
      float mnew = fmaxf(mrun[r], t);
      alpha[r] = __expf(mrun[r] - mnew);
      float p0 = __expf(s[0][r] - mnew);
      float p1 = __expf(s[1][r] - mnew);
      s[0][r] = p0; s[1][r] = p1;
      float ps = p0 + p1;
      ps += __shfl_xor(ps, 1);
      ps += __shfl_xor(ps, 2);
      ps += __shfl_xor(ps, 4);
      ps += __shfl_xor(ps, 8);
      lrun[r] = lrun[r] * alpha[r] + ps;
      mrun[r] = mnew;
    }
    // ---- P -> LDS (row=query, col=key, stride 36) ----
#pragma unroll
    for (int nt = 0; nt < 2; ++nt)
#pragma unroll
      for (int r = 0; r < 4; ++r)
        myP[(quad * 4 + r) * 36 + nt * 16 + la] = s[nt][r];
    __asm__ __volatile__("s_waitcnt lgkmcnt(0)" ::: "memory");
    // ---- P as A-frag (fp16) ----
    fragh pa;
    {
      const f32x4* pr = (const f32x4*)&myP[la * 36 + quad * 8];
      f32x4 p0 = pr[0], p1 = pr[1];
      pa.i4[0] = pkh(p0[0], p0[1]);
      pa.i4[1] = pkh(p0[2], p0[3]);
      pa.i4[2] = pkh(p1[0], p1[1]);
      pa.i4[3] = pkh(p1[2], p1[3]);
    }
    // ---- rescale O, PV ----
#pragma unroll
    for (int mt = 0; mt < 4; ++mt)
#pragma unroll
      for (int r = 0; r < 4; ++r) o[mt][r] *= alpha[r];
#pragma unroll
    for (int mt = 0; mt < 4; ++mt) {
      const int4 vv = *(const int4*)&Vb[(size_t)(mt * 16 + la) * 2048 + (j0 >> 1) + quad * 4];
      fragh vb;
      vb.i4[0] = vv.x; vb.i4[1] = vv.y; vb.i4[2] = vv.z; vb.i4[3] = vv.w;
      o[mt] = __builtin_amdgcn_mfma_f32_16x16x32_f16(pa.h8, vb.h8, o[mt], 0, 0, 0);
    }
  }

  __syncthreads();  // all waves done with P region before union reuse
  if (la == 0) {
#pragma unroll
    for (int r = 0; r < 4; ++r) {
      smu.e.M[wid][quad * 4 + r] = mrun[r];
      smu.e.L[wid][quad * 4 + r] = lrun[r];
    }
  }
#pragma unroll
  for (int mt = 0; mt < 4; ++mt)
#pragma unroll
    for (int r = 0; r < 4; ++r) smu.e.O[wid][quad * 4 + r][mt * 16 + la] = o[mt][r];
  __syncthreads();

#pragma unroll
  for (int t = 0; t < 4; ++t) {
    int oidx = t * 256 + tid;  // 1024 outputs: 16 q x 64 m
    int m = oidx >> 4;
    int q = oidx & 15;
    float m0 = fmaxf(fmaxf(smu.e.M[0][q], smu.e.M[1][q]),
                     fmaxf(smu.e.M[2][q], smu.e.M[3][q]));
    float num = 0.f, den = 0.f;
#pragma unroll
    for (int w = 0; w < 4; ++w) {
      float wgt = __expf(smu.e.M[w][q] - m0);
      num += wgt * smu.e.O[w][q][m];
      den += wgt * smu.e.L[w][q];
    }
    fout[((size_t)b * 64 + m) * N_ + qbase + q] = num / den;
  }
}

// ---------------- f_up conv (K=64, Ot=512) with stats ------------------------------
__global__ __launch_bounds__(256) void convup_k(const float* __restrict__ fout,
                                                const float* __restrict__ wu,
                                                float* __restrict__ u,
                                                float* __restrict__ stats) {
  const int n = blockIdx.x * 256 + threadIdx.x;
  const int b = blockIdx.y;
  const int o0 = blockIdx.z * 8;
  const float* Ap = fout + (size_t)b * 64 * N_ + n;
  const float* Wp = wu + (size_t)o0 * 64;
  float acc[8];
#pragma unroll
  for (int i = 0; i < 8; ++i) acc[i] = 0.f;
#pragma unroll
  for (int c0 = 0; c0 < 64; c0 += 8) {
    float a[8];
#pragma unroll
    for (int cc = 0; cc < 8; ++cc) a[cc] = Ap[(size_t)(c0 + cc) * N_];
#pragma unroll
    for (int i = 0; i < 8; ++i)
#pragma unroll
      for (int cc = 0; cc < 8; ++cc) acc[i] += a[cc] * Wp[(size_t)i * 64 + c0 + cc];
  }
  float* Cp = u + ((size_t)b * 512 + o0) * N_ + n;
#pragma unroll
  for (int i = 0; i < 8; ++i) Cp[(size_t)i * N_] = acc[i];
  const int lane = threadIdx.x & 63;
#pragma unroll
  for (int i = 0; i < 8; ++i) {
    float s = acc[i], q = acc[i] * acc[i];
#pragma unroll
    for (int d = 1; d < 64; d <<= 1) { s += __shfl_xor(s, d); q += __shfl_xor(q, d); }
    if (lane == 0) {
      atomicAdd(&stats[768 + o0 + i], s);
      atomicAdd(&stats[1280 + o0 + i], q);
    }
  }
}

// ---------------- residual + final BN (scale/shift from sums inline) ---------------
__global__ __launch_bounds__(256) void final_k(const float* __restrict__ x,
                                               const float* __restrict__ u,
                                               const float* __restrict__ gu,
                                               const float* __restrict__ bu,
                                               const float* __restrict__ stats,
                                               float* __restrict__ out) {
  size_t idx = (size_t)blockIdx.x * 256 + threadIdx.x;
  int c = (int)((idx >> 12) & 511);
  float mean = stats[768 + c] * (1.f / CNT);
  float var = stats[1280 + c] * (1.f / CNT) - mean * mean;
  float r = rsqrtf(var + 1e-5f);
  float s = gu[c] * r;
  float sh = bu[c] - mean * s;
  out[idx] = x[idx] + u[idx] * s + sh;
}

extern "C" void kernel_launch(void* const* d_in, const int* in_sizes, int n_in,
                              void* d_out, int out_size, void* d_ws, size_t ws_size,
                              hipStream_t stream) {
  const float* x = (const float*)d_in[0];
  const float* y = (const float*)d_in[1];
  const float* ws1 = (const float*)d_in[2];
  const float* gs1 = (const float*)d_in[3];
  const float* bs1 = (const float*)d_in[4];
  const float* ws2 = (const float*)d_in[5];
  const float* gs2 = (const float*)d_in[6];
  const float* bs2 = (const float*)d_in[7];
  const float* wx1 = (const float*)d_in[8];
  const float* gx1 = (const float*)d_in[9];
  const float* bx1 = (const float*)d_in[10];
  const float* wx2 = (const float*)d_in[11];
  const float* gx2 = (const float*)d_in[12];
  const float* bx2 = (const float*)d_in[13];
  const float* wy1 = (const float*)d_in[14];
  const float* gy1 = (const float*)d_in[15];
  const float* by1 = (const float*)d_in[16];
  const float* wy2 = (const float*)d_in[17];
  const float* gy2 = (const float*)d_in[18];
  const float* by2 = (const float*)d_in[19];
  const float* wu = (const float*)d_in[20];
  const float* gu = (const float*)d_in[21];
  const float* bu = (const float*)d_in[22];
  float* out = (float*)d_out;

  float* w = (float*)d_ws;
  const size_t M1 = 1048576;
  float* z1s = w + 0 * M1;
  float* z1x = w + 1 * M1;
  float* z1y = w + 2 * M1;
  float* z2s = w + 3 * M1;
  float* z2x = w + 4 * M1;
  float* z2y = w + 5 * M1;
  float* fout = w + 6 * M1;
  float* u = w + 7 * M1;             // [4][512][4096] = 8 M floats
  int* Qh = (int*)(w + 15 * M1);     // 512K ints
  int* Kh = Qh + 524288;
  int* Vp = Kh + 524288;
  float* stats = w + 15 * M1 + 1572864 / 1;  // after 1.5M ints
  stats = (float*)(Vp + 524288);

  hipMemsetAsync(stats, 0, 1792 * sizeof(float), stream);

  conv1_k<<<dim3(16, 4, 24), dim3(256), 0, stream>>>(x, y, ws1, wx1, wy1, z1s, z1x,
                                                     z1y, stats);
  conv2_k<<<dim3(16, 4, 24), dim3(256), 0, stream>>>(
      z1s, z1x, z1y, ws2, wx2, wy2, gs1, bs1, gx1, bx1, gy1, by1, z2s, z2x, z2y,
      stats);
  pack_k<<<dim3(2048, 1, 3), dim3(256), 0, stream>>>(z2s, z2x, z2y, gs2, bs2, gx2,
                                                     bx2, gy2, by2, Qh, Kh, Vp,
                                                     stats);
  attn_k<<<dim3(1024), dim3(256), 0, stream>>>(Qh, Kh, Vp, fout);
  convup_k<<<dim3(16, 4, 64), dim3(256), 0, stream>>>(fout, wu, u, stats);
  final_k<<<dim3(8192 * 4), dim3(256), 0, stream>>>(x, u, gu, bu, stats, out);
}